// Round 8
// baseline (417.108 us; speedup 1.0000x reference)
//
#include <hip/hip_runtime.h>
#include <stdint.h>

#define OUT_DIM 8192
#define IN_DIM  8192
#define GS      128
#define MROWS   32
#define NSPLIT  8             // split-K chunks of 1024
#define PART_ELEMS (MROWS * OUT_DIM)

typedef __attribute__((ext_vector_type(8))) short bf16x8;   // MFMA A/B frag (4 VGPR)
typedef __attribute__((ext_vector_type(4))) float f32x4;    // MFMA C/D frag
typedef __attribute__((ext_vector_type(8))) unsigned short u16x8;
typedef __attribute__((ext_vector_type(2))) unsigned short u16x2;
typedef __attribute__((ext_vector_type(4))) unsigned int   u32x4;

__device__ __forceinline__ unsigned short f2bf_rne(float f) {
    uint32_t v = __builtin_bit_cast(uint32_t, f);
    v += 0x7FFFu + ((v >> 16) & 1u);
    return (unsigned short)(v >> 16);
}

// x (32x8192 fp32) -> bf16 workspace. Round-0 proven. ~3us.
__global__ __launch_bounds__(256) void prep_xbf(const float* __restrict__ x,
                                                unsigned short* __restrict__ xbf) {
    int i = (blockIdx.x * 256 + threadIdx.x) * 8;
    float4 a = *(const float4*)(x + i);
    float4 b = *(const float4*)(x + i + 4);
    float f[8] = {a.x, a.y, a.z, a.w, b.x, b.y, b.z, b.w};
    u16x8 u;
#pragma unroll
    for (int j = 0; j < 8; ++j) u[j] = f2bf_rne(f[j]);
    *(u16x8*)(xbf + i) = u;
}

// Session finding (R0..R7): every weight-consuming kernel caps at 1.6-2.2 TB/s
// effective read BW regardless of structure (gather/coalesced/LDS/glds) or
// occupancy (R4 2x = null) -> per-CU read-miss concurrency cap. Can't schedule
// around it; SHRINK THE STREAM instead: int32 ternary (4 B/weight) -> 1 B
// (t & 0x81: bit7 = sign iff t==-1, bit0 = |t|). Pure elementwise, fully
// coalesced both sides (copy-class = the one pattern that runs at 6+ TB/s).
// 16 ints/thread, j-strided so every load/store instr is a contiguous run.
__global__ __launch_bounds__(256) void compress_w(const int* __restrict__ t,
                                                  unsigned int* __restrict__ c) {
    const size_t base = (size_t)blockIdx.x * 4096;       // ints per block
    const int tid = threadIdx.x;
#pragma unroll
    for (int j = 0; j < 4; ++j) {
        const size_t ii = base + (size_t)(j << 10) + (size_t)(tid << 2);
        int4 w = *(const int4*)(t + ii);
        unsigned int r = ((unsigned int)w.x & 0x81u)
                       | (((unsigned int)w.y & 0x81u) << 8)
                       | (((unsigned int)w.z & 0x81u) << 16)
                       | (((unsigned int)w.w & 0x81u) << 24);
        c[ii >> 2] = r;                                  // coalesced dword store
    }
}

// Unpack 2 weight-bytes -> dword of 2 bf16 weights (sign/abs-mask + pk_mul,
// session-proven numerics). ssel places bytes at half-MSBs (sign -> bit15),
// asel at half-LSBs (|t| -> bit0). perm src a = 0, sel 0x04.. selects zeros.
__device__ __forceinline__ unsigned int cvt2b(unsigned int dw, unsigned int p32,
                                              unsigned int ssel, unsigned int asel) {
    unsigned int s16 = __builtin_amdgcn_perm(0u, dw, ssel);
    unsigned int a16 = __builtin_amdgcn_perm(0u, dw, asel);
    unsigned int v   = p32 | (s16 & 0x80008000u);
    u16x2 r = __builtin_bit_cast(u16x2, v) *
              __builtin_bit_cast(u16x2, a16 & 0x00010001u);
    return __builtin_bit_cast(unsigned int, r);
}

// 8 weight-bytes (uint2) -> bf16x8 B-fragment, elem j = weight k+j.
__device__ __forceinline__ bf16x8 conv8b(uint2 dw, unsigned int p32) {
    u32x4 d;
    d[0] = cvt2b(dw.x, p32, 0x01040004u, 0x04010400u);   // bytes 0,1
    d[1] = cvt2b(dw.x, p32, 0x03040204u, 0x04030402u);   // bytes 2,3
    d[2] = cvt2b(dw.y, p32, 0x01040004u, 0x04010400u);   // bytes 4,5
    d[3] = cvt2b(dw.y, p32, 0x03040204u, 0x04030402u);   // bytes 6,7
    return __builtin_bit_cast(bf16x8, d);
}

// part[kc][t][o] = sum_{k in chunk kc} x[t][k] * w[o][k] * scale[o*64 + k/128]
// R0/R7-proven skeleton (the ~117us plateau kernel), weights now 1 B each:
// per step one uint2 (8 B/lane) instead of 2x int4 (32 B/lane) -> weight
// stream 64 MiB (L3-hot, just written by compress_w).
__global__ __launch_bounds__(256) void ternary_gemm(
    const unsigned char* __restrict__ comp, const float* __restrict__ scales,
    const unsigned short* __restrict__ xbf, float* __restrict__ part) {
    const int wave  = blockIdx.x * 4 + (threadIdx.x >> 6);
    const int lane  = threadIdx.x & 63;
    const int kc    = wave >> 9;     // 0..7   split-K chunk
    const int ntile = wave & 511;    // 0..511 o-tile
    const int n     = lane & 15;
    const int quad  = lane >> 4;
    const int o      = (ntile << 4) + n;
    const int k0base = kc << 10;

    const unsigned char*  __restrict__ wrow = comp + (size_t)o * IN_DIM;
    const unsigned short* __restrict__ xr0  = xbf + n * IN_DIM;         // x row n
    const unsigned short* __restrict__ xr1  = xbf + (16 + n) * IN_DIM;  // x row 16+n

    const float* __restrict__ sp = scales + o * (IN_DIM / GS) + (kc << 3);
    float s_cur = sp[0];

    f32x4 acc0 = {0.f, 0.f, 0.f, 0.f};
    f32x4 acc1 = {0.f, 0.f, 0.f, 0.f};

#pragma unroll 1   // keep outer loop rolled (R0-proven register budget)
    for (int it = 0; it < 8; ++it) {
        const unsigned int ph  = f2bf_rne(s_cur);
        const unsigned int p32 = ph | (ph << 16);
        float s_nxt = sp[(it < 7) ? (it + 1) : 7];       // prefetch (L1-hot)
        const int k0 = k0base + (it << 7);               // 128-aligned -> one group
#pragma unroll
        for (int st = 0; st < 4; ++st) {
            const int k = k0 + (st << 5) + (quad << 3);  // lane's 8 consecutive k
            uint2 dw = *(const uint2*)(wrow + k);        // 8 weight-bytes
            bf16x8 a0 = *(const bf16x8*)(xr0 + k);
            bf16x8 a1 = *(const bf16x8*)(xr1 + k);
            bf16x8 bfr = conv8b(dw, p32);
            acc0 = __builtin_amdgcn_mfma_f32_16x16x32_bf16(a0, bfr, acc0, 0, 0, 0);
            acc1 = __builtin_amdgcn_mfma_f32_16x16x32_bf16(a1, bfr, acc1, 0, 0, 0);
        }
        s_cur = s_nxt;
    }

    // D layout: col = lane&15 (=o), row t = quad*4 + reg. Plain stores.
    float* __restrict__ prow = part + (size_t)kc * PART_ELEMS;
#pragma unroll
    for (int r = 0; r < 4; ++r) {
        prow[(quad * 4 + r) * OUT_DIM + o]      = acc0[r];
        prow[(quad * 4 + r + 16) * OUT_DIM + o] = acc1[r];
    }
}

// out = sum over 8 split-K partials. 256 blocks x 256 thr x float4.
__global__ __launch_bounds__(256) void reduce_parts(const float* __restrict__ part,
                                                    float* __restrict__ out) {
    const int i = (blockIdx.x * 256 + threadIdx.x) * 4;
    float4 s = *(const float4*)(part + i);
#pragma unroll
    for (int kc = 1; kc < NSPLIT; ++kc) {
        float4 v = *(const float4*)(part + (size_t)kc * PART_ELEMS + i);
        s.x += v.x; s.y += v.y; s.z += v.z; s.w += v.w;
    }
    *(float4*)(out + i) = s;
}

extern "C" void kernel_launch(void* const* d_in, const int* in_sizes, int n_in,
                              void* d_out, int out_size, void* d_ws, size_t ws_size,
                              hipStream_t stream) {
    const float* x      = (const float*)d_in[0];
    const int*   tern   = (const int*)d_in[1];
    const float* scales = (const float*)d_in[2];
    float* out = (float*)d_out;

    unsigned short* xbf  = (unsigned short*)d_ws;                  // 512 KB @ 0
    float*          part = (float*)((char*)d_ws + (512 << 10));    // 8 MB  @ 512K
    unsigned int*   comp = (unsigned int*)((char*)d_ws + (16u << 20)); // 64 MB @ 16M

    compress_w<<<(OUT_DIM * (IN_DIM / 4096)), 256, 0, stream>>>(tern, comp);
    prep_xbf<<<128, 256, 0, stream>>>(x, xbf);
    ternary_gemm<<<1024, 256, 0, stream>>>((const unsigned char*)comp, scales,
                                           xbf, part);
    reduce_parts<<<256, 256, 0, stream>>>(part, out);
}

// Round 9
// 401.016 us; speedup vs baseline: 1.0401x; 1.0401x over previous
//
#include <hip/hip_runtime.h>
#include <stdint.h>

#define OUT_DIM 8192
#define IN_DIM  8192
#define GS      128
#define MROWS   32
#define NSPLIT  16            // split-K chunks of 512
#define KCHUNK  512
#define KSTG    64            // k-ints per pipeline stage
#define NSTG    (KCHUNK / KSTG)   // 8
#define DEPTH   4             // LDS ring buffers (issued stage never hits read buf)
#define PART_ELEMS (MROWS * OUT_DIM)

typedef __attribute__((ext_vector_type(8))) short bf16x8;   // MFMA A/B frag
typedef __attribute__((ext_vector_type(4))) float f32x4;    // MFMA C/D frag
typedef __attribute__((ext_vector_type(8))) unsigned short u16x8;
typedef __attribute__((ext_vector_type(2))) unsigned short u16x2;
typedef __attribute__((ext_vector_type(4))) unsigned int   u32x4;

__device__ __forceinline__ unsigned short f2bf_rne(float f) {
    uint32_t v = __builtin_bit_cast(uint32_t, f);
    v += 0x7FFFu + ((v >> 16) & 1u);
    return (unsigned short)(v >> 16);
}

// x (32x8192 fp32) -> bf16 workspace. Round-0 proven. ~3us.
__global__ __launch_bounds__(256) void prep_xbf(const float* __restrict__ x,
                                                unsigned short* __restrict__ xbf) {
    int i = (blockIdx.x * 256 + threadIdx.x) * 8;
    float4 a = *(const float4*)(x + i);
    float4 b = *(const float4*)(x + i + 4);
    float f[8] = {a.x, a.y, a.z, a.w, b.x, b.y, b.z, b.w};
    u16x8 u;
#pragma unroll
    for (int j = 0; j < 8; ++j) u[j] = f2bf_rne(f[j]);
    *(u16x8*)(xbf + i) = u;
}

// Packed conversion (R6 correctness-proven): two ternary int32 -> one dword of
// two bf16 weights. t in {-1,0,1}: v = p|sign(t); r = v * |t| (v_pk_mul_lo_u16).
__device__ __forceinline__ unsigned int cvt2(int t0, int t1, unsigned int p32) {
    unsigned int t16 = __builtin_amdgcn_perm((unsigned int)t1, (unsigned int)t0,
                                             0x05040100u);
    unsigned int v   = p32 | (t16 & 0x80008000u);
    u16x2 r = __builtin_bit_cast(u16x2, v) *
              __builtin_bit_cast(u16x2, t16 & 0x00010001u);
    return __builtin_bit_cast(unsigned int, r);
}

__device__ __forceinline__ bf16x8 conv8(const int4 wa, const int4 wb, unsigned int p32) {
    u32x4 d;
    d[0] = cvt2(wa.x, wa.y, p32);
    d[1] = cvt2(wa.z, wa.w, p32);
    d[2] = cvt2(wb.x, wb.y, p32);
    d[3] = cvt2(wb.z, wb.w, p32);
    return __builtin_bit_cast(bf16x8, d);
}

__device__ __forceinline__ void glds16(const int* g, int* l) {
    __builtin_amdgcn_global_load_lds(
        (const __attribute__((address_space(1))) void*)g,
        (__attribute__((address_space(3))) void*)l, 16, 0, 0);
}

// R0..R8 finding: every weight-read structure pins at ~2.2 TB/s effective read
// BW while harness fills WRITE at 6.5. All prior structures drained vmcnt(0)
// at each stage (syncthreads) or were gather/TA-serialized -> read pipe duty
// cycle < 100%. This round: T3/T4 counted-vmcnt pipeline, ZERO in-loop
// barriers:
//  - weights: glds into WAVE-PRIVATE LDS rows (wave wv owns rows wv*16..+15),
//    DEPTH=4 ring, 3 stages in flight, s_waitcnt vmcnt(8/4/0) only (never
//    drains while work remains), sched_barrier(0) after each wait (rule #18).
//  - x: staged ONCE per block to LDS (32 KB, one prologue barrier); scales
//    pre-converted to regs -> NO vmem ops in the loop except glds, so the
//    manual vmcnt counts are exact.
//  - rule #21: glds writes linearly -> bank-swizzle applied on the GLOBAL
//    source col (col ^= (row&7)<<3, involution) and on the ds_read col.
// LDS: lw[4][64][64] ints (64KB) + lx[32][520] bf16 (33KB) = 97KB -> 1 blk/CU;
// 4 waves x ~10KB outstanding >> BW*latency (9KB/CU) so line rate is feasible.
__global__ __launch_bounds__(256) void ternary_gemm(
    const int* __restrict__ tern, const float* __restrict__ scales,
    const unsigned short* __restrict__ xbf, float* __restrict__ part) {
    __shared__ __align__(16) int            lw[DEPTH][64][KSTG];   // 64 KB
    __shared__ __align__(16) unsigned short lx[32][KCHUNK + 8];    // 33 KB

    const int tid  = threadIdx.x;
    const int wv   = tid >> 6;
    const int lane = tid & 63;
    const int n    = lane & 15;
    const int quad = lane >> 4;

    const int otile = blockIdx.x & 127;        // 128 o-tiles of 64
    const int kc    = blockIdx.x >> 7;         // 0..15 split-K chunk
    const int o0    = otile << 6;
    const int o     = o0 + (wv << 4) + n;
    const int kpos0 = kc << 9;                 // 512 ints per chunk

    // ---- x staging: 32 rows x 512 k bf16, once per block ----
    {
        const int xrow = tid >> 3;             // 0..31
        const int xc0  = (tid & 7) << 3;       // short col base
        const unsigned short* xs = xbf + (size_t)xrow * IN_DIM + kpos0;
#pragma unroll
        for (int j = 0; j < 8; ++j) {
            const int cs = xc0 + (j << 6);
            *(bf16x8*)&lx[xrow][cs] = *(const bf16x8*)(xs + cs);
        }
    }

    // ---- scales: 4 groups for this (o,kc), pre-converted to packed bf16 ----
    const float* __restrict__ sp = scales + o * (IN_DIM / GS) + (kc << 2);
    unsigned int pga[4];
#pragma unroll
    for (int g = 0; g < 4; ++g) {
        const unsigned int ph = f2bf_rne(sp[g]);
        pga[g] = ph | (ph << 16);
    }

    // ---- glds source addressing (pre-swizzled global col, rule #21) ----
    // instr i covers LDS rows wv*16+4i..+3; lane l -> row_off rl=l>>4,
    // 16B col (l&15). Source col = ((l&15)<<2) ^ ((4(i&1)+rl)<<3).
    const int rl   = lane >> 4;
    const int colA = ((lane & 15) << 2) ^ (rl << 3);          // i = 0, 2
    const int colB = ((lane & 15) << 2) ^ ((4 + rl) << 3);    // i = 1, 3
    const int* __restrict__ gw =
        tern + (size_t)(o0 + (wv << 4) + rl) * IN_DIM + kpos0;

#define GLDS_STAGE(ST) do { const int bu_ = (ST) & 3; const int so_ = (ST) * KSTG; \
        glds16(gw + so_ + colA,                         &lw[bu_][(wv << 4) +  0][0]); \
        glds16(gw + (size_t) 4 * IN_DIM + so_ + colB,   &lw[bu_][(wv << 4) +  4][0]); \
        glds16(gw + (size_t) 8 * IN_DIM + so_ + colA,   &lw[bu_][(wv << 4) +  8][0]); \
        glds16(gw + (size_t)12 * IN_DIM + so_ + colB,   &lw[bu_][(wv << 4) + 12][0]); \
    } while (0)

#define VMWAIT(N) do { asm volatile("s_waitcnt vmcnt(" #N ")" ::: "memory");   \
                       __builtin_amdgcn_sched_barrier(0); } while (0)

    f32x4 acc0 = {0.f, 0.f, 0.f, 0.f};
    f32x4 acc1 = {0.f, 0.f, 0.f, 0.f};

    // prologue: 3 stages in flight; syncthreads drains them (resident) and
    // publishes lx. Pipeline refills from iter 0's issue.
    GLDS_STAGE(0); GLDS_STAGE(1); GLDS_STAGE(2);
    __syncthreads();

    const int lrw = (wv << 4) + n;             // this lane's w row in LDS

#pragma unroll
    for (int s = 0; s < NSTG; ++s) {
        if (s < NSTG - 2)      VMWAIT(8);      // stage s resident, 2 in flight
        else if (s == NSTG - 2) VMWAIT(4);
        else                    VMWAIT(0);
        const unsigned int p32 = pga[s >> 1];  // static after full unroll
        const int bu = s & 3;
#pragma unroll
        for (int h = 0; h < 2; ++h) {
            const int cs  = (h << 5) + (quad << 3);
            const int csw = cs ^ ((n & 7) << 3);
            int4 w0 = *(const int4*)&lw[bu][lrw][csw];
            int4 w1 = *(const int4*)&lw[bu][lrw][csw + 4];
            const int kl = s * KSTG + cs;
            bf16x8 a0 = *(const bf16x8*)&lx[n][kl];
            bf16x8 a1 = *(const bf16x8*)&lx[16 + n][kl];
            bf16x8 bfr = conv8(w0, w1, p32);
            acc0 = __builtin_amdgcn_mfma_f32_16x16x32_bf16(a0, bfr, acc0, 0, 0, 0);
            acc1 = __builtin_amdgcn_mfma_f32_16x16x32_bf16(a1, bfr, acc1, 0, 0, 0);
        }
        if (s + 3 < NSTG) GLDS_STAGE(s + 3);   // issue-after-compute: never
                                               // touches a buffer in {s,s+1,s+2}
    }
#undef GLDS_STAGE
#undef VMWAIT

    // D layout: col = lane&15 (=o), row t = quad*4 + reg. Plain stores.
    float* __restrict__ prow = part + (size_t)kc * PART_ELEMS;
#pragma unroll
    for (int r = 0; r < 4; ++r) {
        prow[(quad * 4 + r) * OUT_DIM + o]      = acc0[r];
        prow[(quad * 4 + r + 16) * OUT_DIM + o] = acc1[r];
    }
}

// out = sum over 16 split-K partials. 256 blocks x 256 thr x float4.
__global__ __launch_bounds__(256) void reduce_parts(const float* __restrict__ part,
                                                    float* __restrict__ out) {
    const int i = (blockIdx.x * 256 + threadIdx.x) * 4;
    float4 s = *(const float4*)(part + i);
#pragma unroll
    for (int kc = 1; kc < NSPLIT; ++kc) {
        float4 v = *(const float4*)(part + (size_t)kc * PART_ELEMS + i);
        s.x += v.x; s.y += v.y; s.z += v.z; s.w += v.w;
    }
    *(float4*)(out + i) = s;
}

extern "C" void kernel_launch(void* const* d_in, const int* in_sizes, int n_in,
                              void* d_out, int out_size, void* d_ws, size_t ws_size,
                              hipStream_t stream) {
    const float* x      = (const float*)d_in[0];
    const int*   tern   = (const int*)d_in[1];
    const float* scales = (const float*)d_in[2];
    float* out = (float*)d_out;

    unsigned short* xbf  = (unsigned short*)d_ws;                  // 512 KB
    float*          part = (float*)((char*)d_ws + (512 << 10));    // 16 MB

    prep_xbf<<<128, 256, 0, stream>>>(x, xbf);
    ternary_gemm<<<128 * NSPLIT, 256, 0, stream>>>(tern, scales, xbf, part);
    reduce_parts<<<256, 256, 0, stream>>>(part, out);
}